// Round 9
// baseline (47.511 us; speedup 1.0000x reference)
//
#include <hip/hip_runtime.h>

#define D8      8
#define LPATH   2048
#define NBATCH  64
#define NSTEPS  2047         // L-1 increments
#define NCHUNK  32
#define CSTEPS  64           // increments per chunk (last chunk: 63)
#define SIGLEN  4680         // 8 + 64 + 512 + 4096
#define OFF2    8
#define OFF3    72
#define OFF4    584
#define APITCH  40           // bf16 elems per row of A/Bt LDS

typedef float  f32x4 __attribute__((ext_vector_type(4)));
typedef short  s16x8 __attribute__((ext_vector_type(8)));

__device__ __forceinline__ void load8(const float* __restrict__ p, float* v) {
    float4 a = ((const float4*)p)[0];
    float4 b = ((const float4*)p)[1];
    v[0]=a.x; v[1]=a.y; v[2]=a.z; v[3]=a.w;
    v[4]=b.x; v[5]=b.y; v[6]=b.z; v[7]=b.w;
}
__device__ __forceinline__ void store8(float* __restrict__ p, const float* v) {
    ((float4*)p)[0] = make_float4(v[0],v[1],v[2],v[3]);
    ((float4*)p)[1] = make_float4(v[4],v[5],v[6],v[7]);
}
__device__ __forceinline__ unsigned int f2bf(float f) {   // RNE f32->bf16 bits
    unsigned int u = __builtin_bit_cast(unsigned int, f);
    u += 0x7FFFu + ((u >> 16) & 1u);
    return u >> 16;
}

// ============================ Phase 1 (MFMA) ============================
// One wave per chunk, 4 chunks per 256-thread block.
// A4 = [C3|C4](64x128) x [H3;H4](128x64) via 16x16x32 bf16 MFMA in 4 K-passes.
__global__ __launch_bounds__(256) void sig_chunk_mfma(const float* __restrict__ path,
                                                      float* __restrict__ sigs) {
    __shared__ float          zl[4][CSTEPS * D8];     // 4 x 2 KB
    __shared__ unsigned short Al[4][64 * APITCH];     // 4 x 5 KB
    __shared__ unsigned short Bl[4][64 * APITCH];     // 4 x 5 KB

    const int w    = threadIdx.x >> 6;
    const int lane = threadIdx.x & 63;
    const int chunk = blockIdx.x * 4 + w;
    const int b    = chunk >> 5;
    const int c    = chunk & (NCHUNK - 1);
    const int t0   = c * CSTEPS;
    const int t1   = (t0 + CSTEPS < NSTEPS) ? (t0 + CSTEPS) : NSTEPS;
    const int n    = t1 - t0;                         // 64 or 63
    const int i    = lane >> 3;
    const int j    = lane & 7;
    const float* __restrict__ pb = path + (size_t)b * LPATH * D8;

    // ---- prologue: z rows into LDS (row lane), zero-fill missing steps ----
    {
        float4 z0, z1;
        if (lane < n) {
            const float* s0 = pb + (size_t)(t0 + lane) * D8;
            float4 a0 = ((const float4*)s0)[0], a1v = ((const float4*)s0)[1];
            float4 b0 = ((const float4*)(s0 + D8))[0], b1v = ((const float4*)(s0 + D8))[1];
            z0 = make_float4(b0.x - a0.x, b0.y - a0.y, b0.z - a0.z, b0.w - a0.w);
            z1 = make_float4(b1v.x - a1v.x, b1v.y - a1v.y, b1v.z - a1v.z, b1v.w - a1v.w);
        } else {
            z0 = make_float4(0.f, 0.f, 0.f, 0.f);
            z1 = z0;
        }
        ((float4*)(&zl[w][lane * D8]))[0] = z0;
        ((float4*)(&zl[w][lane * D8]))[1] = z1;
    }
    __syncthreads();

    const float Tj = pb[(size_t)t1 * D8 + j] - pb[(size_t)t0 * D8 + j];

    float A2 = 0.f, a1i = 0.f, Wl = Tj;
    float A3[8];
#pragma unroll
    for (int k = 0; k < 8; ++k) A3[k] = 0.f;
    f32x4 acc[4][4];
#pragma unroll
    for (int rt = 0; rt < 4; ++rt)
#pragma unroll
        for (int ct = 0; ct < 4; ++ct)
            acc[rt][ct] = (f32x4){0.f, 0.f, 0.f, 0.f};

    float* __restrict__ zw = &zl[w][0];
    unsigned short* __restrict__ Aw = &Al[w][0];
    unsigned short* __restrict__ Bw = &Bl[w][0];

    for (int pass = 0; pass < 4; ++pass) {
        const float* __restrict__ zp = zw + pass * 16 * D8;
#pragma unroll
        for (int bt = 0; bt < 2; ++bt) {
            unsigned int c3pk[4], c4pk[4], h3pk[4], h4pk[4];
#pragma unroll
            for (int e = 0; e < 8; ++e) {
                const int so = (bt * 8 + e) * D8;   // compile-time offset
                float4 za = *(const float4*)(zp + so);
                float4 zb = *(const float4*)(zp + so + 4);
                const float Z[8] = {za.x, za.y, za.z, za.w, zb.x, zb.y, zb.z, zb.w};
                const float Zi = zp[so + i];
                const float Zj = zp[so + j];

                const float p   = Zi * Zj;
                const float uq  = a1i * Zj;
                const float c4v = fmaf(uq, 1.f/6.f, fmaf(p, 1.f/24.f, A2 * 0.5f));
                const float c3v = fmaf(uq, 0.5f,    fmaf(p, 1.f/6.f,  A2));
                Wl -= Zj;
                const float h3v = Zi * Wl;
#pragma unroll
                for (int k = 0; k < 8; ++k) A3[k] = fmaf(c3v, Z[k], A3[k]);
                A2 = A2 + fmaf(p, 0.5f, uq);
                a1i += Zi;

                const unsigned int bc3 = f2bf(c3v), bc4 = f2bf(c4v);
                const unsigned int bh3 = f2bf(h3v), bh4 = f2bf(p);
                if ((e & 1) == 0) {
                    c3pk[e >> 1] = bc3; c4pk[e >> 1] = bc4;
                    h3pk[e >> 1] = bh3; h4pk[e >> 1] = bh4;
                } else {
                    c3pk[e >> 1] |= bc3 << 16; c4pk[e >> 1] |= bc4 << 16;
                    h3pk[e >> 1] |= bh3 << 16; h4pk[e >> 1] |= bh4 << 16;
                }
            }
            *(uint4*)(Aw + lane * APITCH + bt * 8)      = make_uint4(c3pk[0], c3pk[1], c3pk[2], c3pk[3]);
            *(uint4*)(Aw + lane * APITCH + 16 + bt * 8) = make_uint4(c4pk[0], c4pk[1], c4pk[2], c4pk[3]);
            *(uint4*)(Bw + lane * APITCH + bt * 8)      = make_uint4(h3pk[0], h3pk[1], h3pk[2], h3pk[3]);
            *(uint4*)(Bw + lane * APITCH + 16 + bt * 8) = make_uint4(h4pk[0], h4pk[1], h4pk[2], h4pk[3]);
        }
        s16x8 af[4], bfr[4];
#pragma unroll
        for (int rt = 0; rt < 4; ++rt)
            af[rt] = *(const s16x8*)(Aw + (rt * 16 + (lane & 15)) * APITCH + (lane >> 4) * 8);
#pragma unroll
        for (int ct = 0; ct < 4; ++ct)
            bfr[ct] = *(const s16x8*)(Bw + (ct * 16 + (lane & 15)) * APITCH + (lane >> 4) * 8);
#pragma unroll
        for (int rt = 0; rt < 4; ++rt)
#pragma unroll
            for (int ct = 0; ct < 4; ++ct)
                acc[rt][ct] = __builtin_amdgcn_mfma_f32_16x16x32_bf16(af[rt], bfr[ct], acc[rt][ct], 0, 0, 0);
    }

    // ---- epilogue: canonical layout ----
    float* __restrict__ o = sigs + (size_t)chunk * SIGLEN;
    if (lane < 8) o[lane] = pb[(size_t)t1 * D8 + lane] - pb[(size_t)t0 * D8 + lane];
    o[OFF2 + lane] = A2;
    store8(o + OFF3 + lane * 8, A3);
    const int r0 = (lane >> 4) * 4;       // C/D: row=(lane>>4)*4+reg, col=lane&15
    const int cl = lane & 15;
#pragma unroll
    for (int rt = 0; rt < 4; ++rt)
#pragma unroll
        for (int ct = 0; ct < 4; ++ct)
#pragma unroll
            for (int reg = 0; reg < 4; ++reg)
                o[OFF4 + (size_t)(rt * 16 + r0 + reg) * 64 + ct * 16 + cl] = acc[rt][ct][reg];
}

// ============================ Phase 2 ============================
// 8-wave k-split Chen combine: wave w owns k-row w of A3/A4; A1/A2/a1i
// replicated per wave. Manual 2-deep B prefetch (named sets, static idx).

struct BSet {
    float B1[8], b4r[8], b2r[8], b3r[8];
    float b1i, b1j, b2t, b1k, b3k, b2jk;
};

__device__ __forceinline__ void loadB(BSet& S, const float* __restrict__ B,
                                      int lane, int i, int j, int k) {
    load8(B, S.B1);
    S.b1i = B[i];
    S.b1j = B[j];
    S.b2t = B[OFF2 + lane];
    S.b1k = B[k];
    S.b3k = B[OFF3 + lane * 8 + k];
    S.b2jk = B[OFF2 + j * 8 + k];
    load8(B + OFF4 + lane * 64 + k * 8, S.b4r);
    load8(B + OFF2 + k * 8,             S.b2r);
    load8(B + OFF3 + j * 64 + k * 8,    S.b3r);
}

__device__ __forceinline__ void applyB(const BSet& S, float (&A4)[8], float& a3s,
                                       float (&A1)[8], float& A2, float& a1i) {
#pragma unroll
    for (int l = 0; l < 8; ++l) {
        float v = A4[l] + S.b4r[l];
        v = fmaf(a3s, S.B1[l], v);
        v = fmaf(A2,  S.b2r[l], v);
        A4[l] = fmaf(a1i, S.b3r[l], v);
    }
    a3s = fmaf(a1i, S.b2jk, fmaf(A2, S.b1k, a3s + S.b3k));
    A2 = A2 + fmaf(a1i, S.b1j, S.b2t);
#pragma unroll
    for (int m = 0; m < 8; ++m) A1[m] += S.B1[m];
    a1i += S.b1i;
}

template<int NPER>
__global__ __launch_bounds__(512) void sig_combine_kernel(const float* __restrict__ in,
                                                          float* __restrict__ out) {
    const int grp  = blockIdx.x;
    const int tid  = threadIdx.x;
    const int w    = tid >> 6;               // wave id = owned k-row
    const int lane = tid & 63;
    const int i    = lane >> 3;
    const int j    = lane & 7;
    const int k    = w;
    const float* __restrict__ base = in + (size_t)grp * NPER * SIGLEN;

    float A4[8], a3s, A1[8], A2, a1i;
    load8(base, A1);
    a1i = base[i];
    A2  = base[OFF2 + lane];
    a3s = base[OFF3 + lane * 8 + k];
    load8(base + OFF4 + lane * 64 + k * 8, A4);

    BSet Sa, Sb;
    int s = 1;
    loadB(Sa, base + (size_t)s * SIGLEN, lane, i, j, k);
    while (s + 1 < NPER) {
        loadB(Sb, base + (size_t)(s + 1) * SIGLEN, lane, i, j, k);
        applyB(Sa, A4, a3s, A1, A2, a1i);
        ++s;
        if (s + 1 < NPER)
            loadB(Sa, base + (size_t)(s + 1) * SIGLEN, lane, i, j, k);
        applyB(Sb, A4, a3s, A1, A2, a1i);
        ++s;
    }
    if (s < NPER)                              // tail (odd combine count)
        applyB(Sa, A4, a3s, A1, A2, a1i);

    float* __restrict__ o = out + (size_t)grp * SIGLEN;
    if (w == 0) {
        if (lane < 8) o[lane] = A1[lane];
        o[OFF2 + lane] = A2;
    }
    o[OFF3 + lane * 8 + k] = a3s;
    store8(o + OFF4 + lane * 64 + k * 8, A4);
}

extern "C" void kernel_launch(void* const* d_in, const int* in_sizes, int n_in,
                              void* d_out, int out_size, void* d_ws, size_t ws_size,
                              hipStream_t stream) {
    const float* path = (const float*)d_in[0];
    float* out   = (float*)d_out;
    float* sigs  = (float*)d_ws;                                  // 64*32*4680 f32 = 38.3 MB
    float* gsigs = sigs + (size_t)NBATCH * NCHUNK * SIGLEN;       // 64*4*4680 f32 = 4.8 MB

    sig_chunk_mfma<<<NBATCH * NCHUNK / 4, 256, 0, stream>>>(path, sigs);
    sig_combine_kernel<8><<<NBATCH * 4, 512, 0, stream>>>(sigs, gsigs);
    sig_combine_kernel<4><<<NBATCH, 512, 0, stream>>>(gsigs, out);
}

// Round 10
// 31.361 us; speedup vs baseline: 1.5150x; 1.5150x over previous
//
#include <hip/hip_runtime.h>

#define D8      8
#define LPATH   2048
#define NBATCH  64
#define NSTEPS  2047         // L-1 increments
#define NCHUNK  32
#define CSTEPS  64           // increments per chunk (last chunk: 63)
#define SIGLEN  4680         // 8 + 64 + 512 + 4096
#define OFF2    8
#define OFF3    72
#define OFF4    584
#define P4      68           // padded A4 row pitch in LDS sig (272B: 16B-aligned, bank-spread)
#define SIGP    (OFF4 + 64 * P4)   // 4936 floats = 19.7 KB
#define APITCH  40           // bf16 elems per row of A/Bt pack LDS

typedef float  f32x4 __attribute__((ext_vector_type(4)));
typedef short  s16x8 __attribute__((ext_vector_type(8)));

__device__ __forceinline__ void load8(const float* __restrict__ p, float* v) {
    float4 a = ((const float4*)p)[0];
    float4 b = ((const float4*)p)[1];
    v[0]=a.x; v[1]=a.y; v[2]=a.z; v[3]=a.w;
    v[4]=b.x; v[5]=b.y; v[6]=b.z; v[7]=b.w;
}
__device__ __forceinline__ void store8(float* __restrict__ p, const float* v) {
    ((float4*)p)[0] = make_float4(v[0],v[1],v[2],v[3]);
    ((float4*)p)[1] = make_float4(v[4],v[5],v[6],v[7]);
}
__device__ __forceinline__ unsigned int f2bf(float f) {   // RNE f32->bf16 bits
    unsigned int u = __builtin_bit_cast(unsigned int, f);
    u += 0x7FFFu + ((u >> 16) & 1u);
    return u >> 16;
}

// ==================== Phase 1: chunk sigs (MFMA) + in-block fold-8 ====================
// 1 block = 8 waves = 8 consecutive chunks of one batch quarter.
// Main: A4 = [C3|C4](64x128) x [H3;H4](128x64) per chunk via 16x16x32 bf16 MFMA.
// Fold: serial Chen product over the 8 chunk sigs through one padded LDS buffer;
// running sig k-split across the 8 waves (wave w owns k-row w). Output: group sig.

__global__ __launch_bounds__(512) void sig_group_kernel(const float* __restrict__ path,
                                                        float* __restrict__ gsigs) {
    __shared__ __align__(16) float          zl[8][CSTEPS * D8];   // 16 KB
    __shared__ __align__(16) unsigned short Al[8][64 * APITCH];   // 40 KB
    __shared__ __align__(16) unsigned short Bl[8][64 * APITCH];   // 40 KB
    __shared__ __align__(16) float          SB[SIGP];             // 19.7 KB padded sig

    const int w    = threadIdx.x >> 6;            // wave = chunk-in-group AND fold k-row
    const int lane = threadIdx.x & 63;
    const int G    = blockIdx.x & 3;              // group within batch
    const int b    = blockIdx.x >> 2;             // batch
    const int c    = G * 8 + w;                   // chunk within batch
    const int t0   = c * CSTEPS;
    const int t1   = (t0 + CSTEPS < NSTEPS) ? (t0 + CSTEPS) : NSTEPS;
    const int n    = t1 - t0;                     // 64 or 63
    const int i    = lane >> 3;
    const int j    = lane & 7;
    const float* __restrict__ pb = path + (size_t)b * LPATH * D8;

    // ---- prologue: z rows into per-wave LDS, zero-fill missing steps ----
    {
        float4 z0, z1;
        if (lane < n) {
            const float* s0 = pb + (size_t)(t0 + lane) * D8;
            float4 a0 = ((const float4*)s0)[0], a1v = ((const float4*)s0)[1];
            float4 b0 = ((const float4*)(s0 + D8))[0], b1v = ((const float4*)(s0 + D8))[1];
            z0 = make_float4(b0.x - a0.x, b0.y - a0.y, b0.z - a0.z, b0.w - a0.w);
            z1 = make_float4(b1v.x - a1v.x, b1v.y - a1v.y, b1v.z - a1v.z, b1v.w - a1v.w);
        } else {
            z0 = make_float4(0.f, 0.f, 0.f, 0.f);
            z1 = z0;
        }
        ((float4*)(&zl[w][lane * D8]))[0] = z0;
        ((float4*)(&zl[w][lane * D8]))[1] = z1;
    }
    __syncthreads();

    const float Tj = pb[(size_t)t1 * D8 + j] - pb[(size_t)t0 * D8 + j];

    float A2 = 0.f, a1i = 0.f, Wl = Tj;
    float A3[8];
#pragma unroll
    for (int k = 0; k < 8; ++k) A3[k] = 0.f;
    f32x4 acc[4][4];
#pragma unroll
    for (int rt = 0; rt < 4; ++rt)
#pragma unroll
        for (int ct = 0; ct < 4; ++ct)
            acc[rt][ct] = (f32x4){0.f, 0.f, 0.f, 0.f};

    float* __restrict__ zw = &zl[w][0];
    unsigned short* __restrict__ Aw = &Al[w][0];
    unsigned short* __restrict__ Bw = &Bl[w][0];

    for (int pass = 0; pass < 4; ++pass) {
        const float* __restrict__ zp = zw + pass * 16 * D8;
#pragma unroll
        for (int bt = 0; bt < 2; ++bt) {
            unsigned int c3pk[4], c4pk[4], h3pk[4], h4pk[4];
#pragma unroll
            for (int e = 0; e < 8; ++e) {
                const int so = (bt * 8 + e) * D8;   // compile-time offset
                float4 za = *(const float4*)(zp + so);
                float4 zb = *(const float4*)(zp + so + 4);
                const float Z[8] = {za.x, za.y, za.z, za.w, zb.x, zb.y, zb.z, zb.w};
                const float Zi = zp[so + i];
                const float Zj = zp[so + j];

                const float p   = Zi * Zj;
                const float uq  = a1i * Zj;
                const float c4v = fmaf(uq, 1.f/6.f, fmaf(p, 1.f/24.f, A2 * 0.5f));
                const float c3v = fmaf(uq, 0.5f,    fmaf(p, 1.f/6.f,  A2));
                Wl -= Zj;
                const float h3v = Zi * Wl;
#pragma unroll
                for (int k = 0; k < 8; ++k) A3[k] = fmaf(c3v, Z[k], A3[k]);
                A2 = A2 + fmaf(p, 0.5f, uq);
                a1i += Zi;

                const unsigned int bc3 = f2bf(c3v), bc4 = f2bf(c4v);
                const unsigned int bh3 = f2bf(h3v), bh4 = f2bf(p);
                if ((e & 1) == 0) {
                    c3pk[e >> 1] = bc3; c4pk[e >> 1] = bc4;
                    h3pk[e >> 1] = bh3; h4pk[e >> 1] = bh4;
                } else {
                    c3pk[e >> 1] |= bc3 << 16; c4pk[e >> 1] |= bc4 << 16;
                    h3pk[e >> 1] |= bh3 << 16; h4pk[e >> 1] |= bh4 << 16;
                }
            }
            *(uint4*)(Aw + lane * APITCH + bt * 8)      = make_uint4(c3pk[0], c3pk[1], c3pk[2], c3pk[3]);
            *(uint4*)(Aw + lane * APITCH + 16 + bt * 8) = make_uint4(c4pk[0], c4pk[1], c4pk[2], c4pk[3]);
            *(uint4*)(Bw + lane * APITCH + bt * 8)      = make_uint4(h3pk[0], h3pk[1], h3pk[2], h3pk[3]);
            *(uint4*)(Bw + lane * APITCH + 16 + bt * 8) = make_uint4(h4pk[0], h4pk[1], h4pk[2], h4pk[3]);
        }
        s16x8 af[4], bfr[4];
#pragma unroll
        for (int rt = 0; rt < 4; ++rt)
            af[rt] = *(const s16x8*)(Aw + (rt * 16 + (lane & 15)) * APITCH + (lane >> 4) * 8);
#pragma unroll
        for (int ct = 0; ct < 4; ++ct)
            bfr[ct] = *(const s16x8*)(Bw + (ct * 16 + (lane & 15)) * APITCH + (lane >> 4) * 8);
#pragma unroll
        for (int rt = 0; rt < 4; ++rt)
#pragma unroll
            for (int ct = 0; ct < 4; ++ct)
                acc[rt][ct] = __builtin_amdgcn_mfma_f32_16x16x32_bf16(af[rt], bfr[ct], acc[rt][ct], 0, 0, 0);
    }

    // ==================== in-block fold-8 (Chen, left-to-right) ====================
    // dump wave-s chunk sig into padded LDS buffer SB
    const int r0 = (lane >> 4) * 4;
    const int cl = lane & 15;

    // running (folded) sig, k-split: wave w owns k-row w
    float FA4[8], fa3, FA1[8], FA2, fa1i;

    __syncthreads();
    for (int s = 0; s < 8; ++s) {
        if (w == s) {   // dump my chunk sig to SB
            if ((lane & 7) == 0) SB[lane >> 3] = a1i;     // A1[i] (lane 8i has j=0)
            SB[OFF2 + lane] = A2;
#pragma unroll
            for (int k = 0; k < 8; ++k) SB[OFF3 + lane * 8 + k] = A3[k];
#pragma unroll
            for (int rt = 0; rt < 4; ++rt)
#pragma unroll
                for (int ct = 0; ct < 4; ++ct)
#pragma unroll
                    for (int reg = 0; reg < 4; ++reg)
                        SB[OFF4 + (rt * 16 + r0 + reg) * P4 + ct * 16 + cl] = acc[rt][ct][reg];
        }
        __syncthreads();
        if (s == 0) {   // initialize running sig from wave-0's dump
            load8(SB, FA1);
            fa1i = SB[i];
            FA2  = SB[OFF2 + lane];
            fa3  = SB[OFF3 + lane * 8 + w];
            load8(SB + OFF4 + lane * P4 + w * 8, FA4);
        } else {        // running = running (x) SB   [k-split: k = w]
            float B1[8]; load8(SB, B1);
            const float b1i = SB[i];
            const float b1j = SB[j];
            const float b2t = SB[OFF2 + lane];
            const float b1k = SB[w];
            const float b3k = SB[OFF3 + lane * 8 + w];
            const float b2jk = SB[OFF2 + j * 8 + w];
            float b4r[8], b2r[8], b3r[8];
            load8(SB + OFF4 + lane * P4 + w * 8, b4r);
            load8(SB + OFF2 + w * 8,             b2r);
            load8(SB + OFF3 + (j * 8 + w) * 8,   b3r);
#pragma unroll
            for (int l = 0; l < 8; ++l) {
                float v = FA4[l] + b4r[l];
                v = fmaf(fa3,  B1[l], v);
                v = fmaf(FA2,  b2r[l], v);
                FA4[l] = fmaf(fa1i, b3r[l], v);
            }
            fa3 = fmaf(fa1i, b2jk, fmaf(FA2, b1k, fa3 + b3k));
            FA2 = FA2 + fmaf(fa1i, b1j, b2t);
#pragma unroll
            for (int m = 0; m < 8; ++m) FA1[m] += B1[m];
            fa1i += b1i;
        }
        __syncthreads();
    }

    // ---- write group sig (canonical layout) ----
    float* __restrict__ o = gsigs + (size_t)blockIdx.x * SIGLEN;
    if (w == 0) {
        if (lane < 8) o[lane] = FA1[lane];
        o[OFF2 + lane] = FA2;
    }
    o[OFF3 + lane * 8 + w] = fa3;
    store8(o + OFF4 + lane * 64 + w * 8, FA4);
}

// ==================== Phase 2: fold the 4 group sigs per batch ====================
struct BSet {
    float B1[8], b4r[8], b2r[8], b3r[8];
    float b1i, b1j, b2t, b1k, b3k, b2jk;
};

__device__ __forceinline__ void loadB(BSet& S, const float* __restrict__ B,
                                      int lane, int i, int j, int k) {
    load8(B, S.B1);
    S.b1i = B[i];
    S.b1j = B[j];
    S.b2t = B[OFF2 + lane];
    S.b1k = B[k];
    S.b3k = B[OFF3 + lane * 8 + k];
    S.b2jk = B[OFF2 + j * 8 + k];
    load8(B + OFF4 + lane * 64 + k * 8, S.b4r);
    load8(B + OFF2 + k * 8,             S.b2r);
    load8(B + OFF3 + j * 64 + k * 8,    S.b3r);
}

__device__ __forceinline__ void applyB(const BSet& S, float (&A4)[8], float& a3s,
                                       float (&A1)[8], float& A2, float& a1i) {
#pragma unroll
    for (int l = 0; l < 8; ++l) {
        float v = A4[l] + S.b4r[l];
        v = fmaf(a3s, S.B1[l], v);
        v = fmaf(A2,  S.b2r[l], v);
        A4[l] = fmaf(a1i, S.b3r[l], v);
    }
    a3s = fmaf(a1i, S.b2jk, fmaf(A2, S.b1k, a3s + S.b3k));
    A2 = A2 + fmaf(a1i, S.b1j, S.b2t);
#pragma unroll
    for (int m = 0; m < 8; ++m) A1[m] += S.B1[m];
    a1i += S.b1i;
}

template<int NPER>
__global__ __launch_bounds__(512) void sig_combine_kernel(const float* __restrict__ in,
                                                          float* __restrict__ out) {
    const int grp  = blockIdx.x;
    const int tid  = threadIdx.x;
    const int w    = tid >> 6;               // wave id = owned k-row
    const int lane = tid & 63;
    const int i    = lane >> 3;
    const int j    = lane & 7;
    const int k    = w;
    const float* __restrict__ base = in + (size_t)grp * NPER * SIGLEN;

    float A4[8], a3s, A1[8], A2, a1i;
    load8(base, A1);
    a1i = base[i];
    A2  = base[OFF2 + lane];
    a3s = base[OFF3 + lane * 8 + k];
    load8(base + OFF4 + lane * 64 + k * 8, A4);

    BSet Sa, Sb;
    int s = 1;
    loadB(Sa, base + (size_t)s * SIGLEN, lane, i, j, k);
    while (s + 1 < NPER) {
        loadB(Sb, base + (size_t)(s + 1) * SIGLEN, lane, i, j, k);
        applyB(Sa, A4, a3s, A1, A2, a1i);
        ++s;
        if (s + 1 < NPER)
            loadB(Sa, base + (size_t)(s + 1) * SIGLEN, lane, i, j, k);
        applyB(Sb, A4, a3s, A1, A2, a1i);
        ++s;
    }
    if (s < NPER)
        applyB(Sa, A4, a3s, A1, A2, a1i);

    float* __restrict__ o = out + (size_t)grp * SIGLEN;
    if (w == 0) {
        if (lane < 8) o[lane] = A1[lane];
        o[OFF2 + lane] = A2;
    }
    o[OFF3 + lane * 8 + k] = a3s;
    store8(o + OFF4 + lane * 64 + k * 8, A4);
}

extern "C" void kernel_launch(void* const* d_in, const int* in_sizes, int n_in,
                              void* d_out, int out_size, void* d_ws, size_t ws_size,
                              hipStream_t stream) {
    const float* path = (const float*)d_in[0];
    float* out   = (float*)d_out;
    float* gsigs = (float*)d_ws;              // 64*4*4680 f32 = 4.8 MB

    sig_group_kernel<<<NBATCH * 4, 512, 0, stream>>>(path, gsigs);
    sig_combine_kernel<4><<<NBATCH, 512, 0, stream>>>(gsigs, out);
}